// Round 1
// baseline (1649.404 us; speedup 1.0000x reference)
//
#include <hip/hip_runtime.h>

// Shapes
#define B_N   256
#define C_IN  64
#define C_OUT 128
#define T_N   64
#define V_N   25
#define TV    1600        // T*V
#define XB    102400      // Cin*T*V  (x per batch)
#define OB    204800      // Cout*T*V (out per batch)

// ws float offsets
#define WS_WYT   0         // Wy_t[192][128]
#define WS_WRT   24576     // Wr_t[64][128]
#define WS_BIASY 32768     // bias_y[128][25]
#define WS_STATS 36864     // [sum_y|ss_y|sum_r|ss_r] x128
#define WS_AFF   37376     // [ay,by,ar,br] x128
#define WS_RBUF  40960     // r buffer, 52428800 floats

// LDS strides (bank-conflict padding)
#define XS_S 105
#define XA_S 105
#define WL_S 132

__global__ void prep_kernel(const float* __restrict__ PA, const float* __restrict__ Wv,
                            const float* __restrict__ bv, const float* __restrict__ Wr,
                            float* __restrict__ ws)
{
    int tid = blockIdx.x * blockDim.x + threadIdx.x;
    int nthr = gridDim.x * blockDim.x;
    // Wy_t[hc][o] = Wv[h][o][c],  hc = h*64+c
    for (int f = tid; f < 192 * 128; f += nthr) {
        int hc = f >> 7, o = f & 127;
        int h = hc >> 6, c = hc & 63;
        ws[WS_WYT + f] = Wv[(h * C_OUT + o) * C_IN + c];
    }
    // Wr_t[c][o] = Wr[o][c]
    for (int f = tid; f < 64 * 128; f += nthr) {
        int c = f >> 7, o = f & 127;
        ws[WS_WRT + f] = Wr[o * C_IN + c];
    }
    // bias_y[o][i] = sum_h bv[h][o] * sum_j PA[h][i][j]
    for (int f = tid; f < 128 * 25; f += nthr) {
        int o = f / 25, i = f % 25;
        float s = 0.f;
        for (int h = 0; h < 3; ++h) {
            float rs = 0.f;
            for (int j = 0; j < 25; ++j) rs += PA[(h * 25 + i) * 25 + j];
            s = fmaf(bv[h * C_OUT + o], rs, s);
        }
        ws[WS_BIASY + f] = s;
    }
    for (int f = tid; f < 512; f += nthr) ws[WS_STATS + f] = 0.f;
}

// One WG per (b, block of 4 t). 320 threads: ty(16) x tx(20); thread owns 8 rows x 5 cols.
__global__ __launch_bounds__(320) void pass_a(
    const float* __restrict__ x, const float* __restrict__ PA,
    const float* __restrict__ br, float* __restrict__ out, float* __restrict__ ws)
{
    __shared__ float xs[64 * XS_S];   // x tile [c][tt*25+j], also reused for store transpose
    __shared__ float xa[32 * XA_S];   // xa chunk [cc][tt*25+i]
    __shared__ float wl[32 * WL_S];   // weight chunk [k][o]
    __shared__ float stl[512];        // per-WG stats

    const float* __restrict__ WYT   = ws + WS_WYT;
    const float* __restrict__ WRT   = ws + WS_WRT;
    const float* __restrict__ BIASY = ws + WS_BIASY;
    float* STATS = ws + WS_STATS;
    float* RBUF  = ws + WS_RBUF;

    const int tid = threadIdx.x;
    const int b   = blockIdx.x >> 4;
    const int tb  = blockIdx.x & 15;
    const int t0  = tb * 4;

    for (int f = tid; f < 512; f += 320) stl[f] = 0.f;

    // stage x tile: 64 rows x 100 floats (coalesced float4)
    const float* xb = x + b * XB + t0 * 25;
    for (int idx = tid; idx < 1600; idx += 320) {
        int c = idx / 25, p4 = idx % 25;
        float4 v = *(const float4*)(xb + c * TV + p4 * 4);
        float* d = &xs[c * XS_S + p4 * 4];
        d[0] = v.x; d[1] = v.y; d[2] = v.z; d[3] = v.w;
    }
    __syncthreads();

    const int ty = tid / 20;       // 0..15 -> rows ty*8..ty*8+7
    const int tx = tid % 20;       // 0..19 -> cols tx*5..tx*5+4
    const int tt = tx / 5;         // t within block (cols never cross a t boundary: 5|25)
    const int i0 = (tx % 5) * 5;   // base i within V

    float accy[8][5], accr[8][5];
    #pragma unroll
    for (int rr = 0; rr < 8; ++rr)
        #pragma unroll
        for (int jj = 0; jj < 5; ++jj) { accy[rr][jj] = 0.f; accr[rr][jj] = 0.f; }

    // ---- y GEMM: K=192 in 6 chunks of 32 ----
    for (int kc = 0; kc < 6; ++kc) {
        // stage Wy chunk [32][128]
        for (int idx = tid; idx < 1024; idx += 320) {
            int k = idx >> 5, o4 = idx & 31;
            *(float4*)(&wl[k * WL_S + o4 * 4]) = *(const float4*)(WYT + (kc * 32 + k) * 128 + o4 * 4);
        }
        // compute xa chunk: rows hc = kc*32 + cc
        if (tid < 256) {
            int cc = tid & 31;
            int ct = (tid >> 5) & 3;
            int sh = tid >> 7;
            int hc = kc * 32 + cc;
            int h = hc >> 6, c = hc & 63;
            float xr[25];
            #pragma unroll
            for (int j = 0; j < 25; ++j) xr[j] = xs[c * XS_S + ct * 25 + j];
            const float* __restrict__ pa = PA + h * 625;   // uniform -> scalar loads
            int ia = sh ? 12 : 0, ib2 = sh ? 25 : 12;
            for (int i = ia; i < ib2; ++i) {
                float acc = 0.f;
                #pragma unroll
                for (int j = 0; j < 25; ++j) acc = fmaf(pa[i * 25 + j], xr[j], acc);
                xa[cc * XA_S + ct * 25 + i] = acc;
            }
        }
        __syncthreads();
        #pragma unroll 4
        for (int k = 0; k < 32; ++k) {
            float4 a0 = *(const float4*)(&wl[k * WL_S + ty * 8]);
            float4 a1 = *(const float4*)(&wl[k * WL_S + ty * 8 + 4]);
            float a[8] = {a0.x, a0.y, a0.z, a0.w, a1.x, a1.y, a1.z, a1.w};
            float bb[5];
            #pragma unroll
            for (int jj = 0; jj < 5; ++jj) bb[jj] = xa[k * XA_S + tx * 5 + jj];
            #pragma unroll
            for (int rr = 0; rr < 8; ++rr)
                #pragma unroll
                for (int jj = 0; jj < 5; ++jj)
                    accy[rr][jj] = fmaf(a[rr], bb[jj], accy[rr][jj]);
        }
        __syncthreads();
    }

    // ---- r GEMM: K=64 in 2 chunks of 32, B-operand = xs directly ----
    for (int rc = 0; rc < 2; ++rc) {
        for (int idx = tid; idx < 1024; idx += 320) {
            int k = idx >> 5, o4 = idx & 31;
            *(float4*)(&wl[k * WL_S + o4 * 4]) = *(const float4*)(WRT + (rc * 32 + k) * 128 + o4 * 4);
        }
        __syncthreads();
        #pragma unroll 4
        for (int k = 0; k < 32; ++k) {
            float4 a0 = *(const float4*)(&wl[k * WL_S + ty * 8]);
            float4 a1 = *(const float4*)(&wl[k * WL_S + ty * 8 + 4]);
            float a[8] = {a0.x, a0.y, a0.z, a0.w, a1.x, a1.y, a1.z, a1.w};
            float bb[5];
            #pragma unroll
            for (int jj = 0; jj < 5; ++jj) bb[jj] = xs[(rc * 32 + k) * XS_S + tx * 5 + jj];
            #pragma unroll
            for (int rr = 0; rr < 8; ++rr)
                #pragma unroll
                for (int jj = 0; jj < 5; ++jj)
                    accr[rr][jj] = fmaf(a[rr], bb[jj], accr[rr][jj]);
        }
        __syncthreads();
    }

    // ---- epilogue: bias + per-channel stats ----
    #pragma unroll
    for (int rr = 0; rr < 8; ++rr) {
        int o = ty * 8 + rr;
        float s = 0.f, ss = 0.f;
        #pragma unroll
        for (int jj = 0; jj < 5; ++jj) {
            float v = accy[rr][jj] + BIASY[o * 25 + i0 + jj];
            accy[rr][jj] = v;
            s += v; ss = fmaf(v, v, ss);
        }
        atomicAdd(&stl[o], s);
        atomicAdd(&stl[128 + o], ss);
    }
    #pragma unroll
    for (int rr = 0; rr < 8; ++rr) {
        int o = ty * 8 + rr;
        float bo = br[o];
        float s = 0.f, ss = 0.f;
        #pragma unroll
        for (int jj = 0; jj < 5; ++jj) {
            float v = accr[rr][jj] + bo;
            accr[rr][jj] = v;
            s += v; ss = fmaf(v, v, ss);
        }
        atomicAdd(&stl[256 + o], s);
        atomicAdd(&stl[384 + o], ss);
    }
    __syncthreads();
    for (int f = tid; f < 512; f += 320) atomicAdd(&STATS[f], stl[f]);

    // ---- coalesced stores via LDS transpose (reuse xs), 64-row halves ----
    for (int half = 0; half < 2; ++half) {
        const int obase = b * OB + half * 64 * TV + t0 * 25;
        // y
        if ((ty >> 3) == half) {
            int rl = (ty & 7) * 8;
            #pragma unroll
            for (int rr = 0; rr < 8; ++rr)
                #pragma unroll
                for (int jj = 0; jj < 5; ++jj)
                    xs[(rl + rr) * XS_S + tt * 25 + i0 + jj] = accy[rr][jj];
        }
        __syncthreads();
        for (int idx = tid; idx < 1600; idx += 320) {
            int r = idx / 25, p4 = idx % 25;
            const float* s4 = &xs[r * XS_S + p4 * 4];
            float4 v = {s4[0], s4[1], s4[2], s4[3]};
            *(float4*)(out + obase + r * TV + p4 * 4) = v;
        }
        __syncthreads();
        // r
        if ((ty >> 3) == half) {
            int rl = (ty & 7) * 8;
            #pragma unroll
            for (int rr = 0; rr < 8; ++rr)
                #pragma unroll
                for (int jj = 0; jj < 5; ++jj)
                    xs[(rl + rr) * XS_S + tt * 25 + i0 + jj] = accr[rr][jj];
        }
        __syncthreads();
        for (int idx = tid; idx < 1600; idx += 320) {
            int r = idx / 25, p4 = idx % 25;
            const float* s4 = &xs[r * XS_S + p4 * 4];
            float4 v = {s4[0], s4[1], s4[2], s4[3]};
            *(float4*)(RBUF + obase + r * TV + p4 * 4) = v;
        }
        __syncthreads();
    }
}

__global__ void pass_b(const float* __restrict__ gamma, const float* __restrict__ beta,
                       const float* __restrict__ gamma_r, const float* __restrict__ beta_r,
                       float* __restrict__ ws)
{
    int o = threadIdx.x;
    if (o >= 128) return;
    const float inv = 1.0f / 409600.0f;
    float* STATS = ws + WS_STATS;
    float my = STATS[o] * inv;
    float vy = STATS[128 + o] * inv - my * my;
    float ay = gamma[o] * rsqrtf(vy + 1e-5f);
    float by = beta[o] - ay * my;
    float mr = STATS[256 + o] * inv;
    float vr = STATS[384 + o] * inv - mr * mr;
    float ar = gamma_r[o] * rsqrtf(vr + 1e-5f);
    float brf = beta_r[o] - ar * mr;
    float4 v = {ay, by, ar, brf};
    *(float4*)(ws + WS_AFF + o * 4) = v;
}

__global__ __launch_bounds__(256) void pass_c(float* __restrict__ out, const float* __restrict__ ws)
{
    const float4* __restrict__ rb = (const float4*)(ws + WS_RBUF);
    const float4* __restrict__ af = (const float4*)(ws + WS_AFF);
    float4* __restrict__ o4 = (float4*)out;
    const int total4 = 13107200;                 // 52428800 / 4
    for (int i4 = blockIdx.x * 256 + threadIdx.x; i4 < total4; i4 += gridDim.x * 256) {
        float4 y = o4[i4];
        float4 r = rb[i4];
        int ch = (i4 / 400) & 127;               // (i4*4/1600) % 128
        float4 a = af[ch];
        float4 res;
        res.x = fmaxf(0.f, fmaf(a.x, y.x, a.y) + fmaf(a.z, r.x, a.w));
        res.y = fmaxf(0.f, fmaf(a.x, y.y, a.y) + fmaf(a.z, r.y, a.w));
        res.z = fmaxf(0.f, fmaf(a.x, y.z, a.y) + fmaf(a.z, r.z, a.w));
        res.w = fmaxf(0.f, fmaf(a.x, y.w, a.y) + fmaf(a.z, r.w, a.w));
        o4[i4] = res;
    }
}

extern "C" void kernel_launch(void* const* d_in, const int* in_sizes, int n_in,
                              void* d_out, int out_size, void* d_ws, size_t ws_size,
                              hipStream_t stream) {
    const float* x       = (const float*)d_in[0];
    const float* PA      = (const float*)d_in[1];
    const float* Wv      = (const float*)d_in[2];
    const float* bv      = (const float*)d_in[3];
    const float* gamma   = (const float*)d_in[4];
    const float* beta    = (const float*)d_in[5];
    const float* Wr      = (const float*)d_in[6];
    const float* br      = (const float*)d_in[7];
    const float* gamma_r = (const float*)d_in[8];
    const float* beta_r  = (const float*)d_in[9];
    float* out = (float*)d_out;
    float* ws  = (float*)d_ws;

    prep_kernel<<<32, 256, 0, stream>>>(PA, Wv, bv, Wr, ws);
    pass_a<<<4096, 320, 0, stream>>>(x, PA, br, out, ws);
    pass_b<<<1, 128, 0, stream>>>(gamma, beta, gamma_r, beta_r, ws);
    pass_c<<<2048, 256, 0, stream>>>(out, ws);
}

// Round 2
// 831.518 us; speedup vs baseline: 1.9836x; 1.9836x over previous
//
#include <hip/hip_runtime.h>

typedef unsigned short u16;
typedef float f32x4 __attribute__((ext_vector_type(4)));
typedef short bf16x8 __attribute__((ext_vector_type(8)));

// Shapes
#define XB    102400      // Cin*T*V  (x per batch)
#define TV    1600        // T*V
#define OB    204800      // Cout*T*V
#define NTOT  409600      // B*T*V columns
#define WGN   128         // columns per WG
#define NWG   3200        // NTOT/WGN
#define MW    7           // t-window (distinct b*64+t values) per WG
#define XT_S  68          // LDS stride for x_t rows (16B-aligned, spreads banks)

// ws float offsets
#define WS_PAH   0        // packed A hi (unscaled), 32768 u16 = 16384 f
#define WS_PAL   16384
#define WS_PSH   32768    // packed A hi (scaled by BN affine)
#define WS_PSL   49152
#define WS_BIASY 65536    // bias_y[128][25]
#define WS_C0    68736    // C0[128][25]
#define WS_STATS 71936    // [sum_y|ss_y|sum_r|ss_r] x128
#define WS_AFF   72448    // [ay,by,ar,brf] x128

__device__ __forceinline__ u16 f2bf(float x) {
    unsigned u = __float_as_uint(x);
    return (u16)((u + 0x7fffu + ((u >> 16) & 1u)) >> 16);
}
__device__ __forceinline__ void split2(float x, u16& h, u16& l) {
    h = f2bf(x);
    float hf = __uint_as_float(((unsigned)h) << 16);
    l = f2bf(x - hf);
}
// packed-weight index decode: idx -> (k, o)
__device__ __forceinline__ void decode_pack(int idx, int& k, int& o) {
    int kt = idx >> 12, Mt = (idx >> 9) & 7, ln = (idx >> 3) & 63, e = idx & 7;
    k = kt * 32 + ((ln >> 4) << 3) + e;
    o = Mt * 16 + (ln & 15);
}

__global__ void prep(const float* __restrict__ PA, const float* __restrict__ Wv,
                     const float* __restrict__ bv, const float* __restrict__ Wr,
                     float* __restrict__ ws)
{
    int tid = blockIdx.x * blockDim.x + threadIdx.x;
    int nthr = gridDim.x * blockDim.x;
    u16* PH = (u16*)(ws + WS_PAH);
    u16* PL = (u16*)(ws + WS_PAL);
    for (int idx = tid; idx < 32768; idx += nthr) {
        int k, o; decode_pack(idx, k, o);
        float w = (k < 192) ? Wv[(((k >> 6) * 128) + o) * 64 + (k & 63)]
                            : Wr[o * 64 + (k - 192)];
        u16 hh, ll; split2(w, hh, ll);
        PH[idx] = hh; PL[idx] = ll;
    }
    for (int f = tid; f < 128 * 25; f += nthr) {
        int o = f / 25, i = f % 25;
        float s = 0.f;
        for (int h = 0; h < 3; ++h) {
            float rs = 0.f;
            for (int j = 0; j < 25; ++j) rs += PA[(h * 25 + i) * 25 + j];
            s = fmaf(bv[h * 128 + o], rs, s);
        }
        ws[WS_BIASY + f] = s;
    }
    for (int f = tid; f < 512; f += nthr) ws[WS_STATS + f] = 0.f;
}

__device__ __forceinline__ void frag_mma(int kt, int g, int lane, int mloc, int icol,
    const float* __restrict__ xt, const float* __restrict__ pa_s,
    const u16* __restrict__ WH, const u16* __restrict__ WL, f32x4* acc)
{
    float a8[8];
    if (kt < 6) {
        // xa rows: hc = kt*32 + g*8 + e ; h = kt>>1, c = (kt&1)*32 + g*8 + e
        int c0 = ((kt & 1) << 5) + (g << 3);
        const float* pb = pa_s + (kt >> 1) * 625 + icol * 25;
        const float* xb = xt + mloc * 25 * XT_S + c0;
        #pragma unroll
        for (int e = 0; e < 8; ++e) a8[e] = 0.f;
        #pragma unroll
        for (int j = 0; j < 25; ++j) {
            float p = pb[j];
            f32x4 v0 = *(const f32x4*)(xb + j * XT_S);
            f32x4 v1 = *(const f32x4*)(xb + j * XT_S + 4);
            a8[0] = fmaf(p, v0[0], a8[0]); a8[1] = fmaf(p, v0[1], a8[1]);
            a8[2] = fmaf(p, v0[2], a8[2]); a8[3] = fmaf(p, v0[3], a8[3]);
            a8[4] = fmaf(p, v1[0], a8[4]); a8[5] = fmaf(p, v1[1], a8[5]);
            a8[6] = fmaf(p, v1[2], a8[6]); a8[7] = fmaf(p, v1[3], a8[7]);
        }
    } else {
        // x rows: c = (kt-6)*32 + g*8 + e, column's own (m, i)
        int c0 = ((kt - 6) << 5) + (g << 3);
        const float* xb = xt + (mloc * 25 + icol) * XT_S + c0;
        f32x4 v0 = *(const f32x4*)(xb);
        f32x4 v1 = *(const f32x4*)(xb + 4);
        a8[0] = v0[0]; a8[1] = v0[1]; a8[2] = v0[2]; a8[3] = v0[3];
        a8[4] = v1[0]; a8[5] = v1[1]; a8[6] = v1[2]; a8[7] = v1[3];
    }
    bf16x8 bh, bl;
    #pragma unroll
    for (int e = 0; e < 8; ++e) {
        u16 hh, ll; split2(a8[e], hh, ll);
        bh[e] = (short)hh; bl[e] = (short)ll;
    }
    const bf16x8* AH = ((const bf16x8*)WH) + kt * 512 + lane;
    const bf16x8* AL = ((const bf16x8*)WL) + kt * 512 + lane;
    #pragma unroll
    for (int Mt = 0; Mt < 8; ++Mt) {
        bf16x8 ah = AH[Mt * 64];
        bf16x8 al = AL[Mt * 64];
        acc[Mt] = __builtin_amdgcn_mfma_f32_16x16x32_bf16(ah, bh, acc[Mt], 0, 0, 0);
        acc[Mt] = __builtin_amdgcn_mfma_f32_16x16x32_bf16(ah, bl, acc[Mt], 0, 0, 0);
        acc[Mt] = __builtin_amdgcn_mfma_f32_16x16x32_bf16(al, bh, acc[Mt], 0, 0, 0);
    }
}

// MODE 0: stats pass (unscaled weights, accumulate sum/ss). MODE 1: store pass.
template<int MODE>
__global__ __launch_bounds__(512, 2) void gsa_main(
    const float* __restrict__ x, const float* __restrict__ PA,
    const float* __restrict__ br, float* __restrict__ out, float* __restrict__ ws)
{
    __shared__ float xt[MW * 25 * XT_S];   // 175 rows x 68 = 47.6 KB
    __shared__ float pa_s[1875];
    __shared__ float stl[512];

    const int tid = threadIdx.x;
    const int wg  = blockIdx.x;
    const int n0  = wg * WGN;
    const int m0  = n0 / 25;

    for (int idx = tid; idx < 1875; idx += 512) pa_s[idx] = PA[idx];
    if (MODE == 0) { if (tid < 512) stl[tid] = 0.f; }

    // stage x window: mi in [0,MW), c in [0,64), 7 aligned float4 granules/row
    for (int idx = tid; idx < MW * 64 * 7; idx += 512) {
        int mi = idx / 448; int rem = idx - mi * 448;
        int c = rem / 7;    int jq = rem - c * 7;
        int m = m0 + mi; if (m > 16383) m = 16383;
        int b = m >> 6, t = m & 63;
        int g0 = (t * 25) >> 2;
        int q = g0 + jq;
        f32x4 v = *(const f32x4*)(x + b * XB + c * TV + q * 4);
        int jbase = q * 4 - t * 25;
        #pragma unroll
        for (int u = 0; u < 4; ++u) {
            int j = jbase + u;
            if (j >= 0 && j < 25) xt[(mi * 25 + j) * XT_S + c] = v[u];
        }
    }
    __syncthreads();

    const int lane = tid & 63, w = tid >> 6;
    const int g = lane >> 4, l15 = lane & 15;
    const int n = n0 + w * 16 + l15;
    const int mloc = n / 25 - m0;
    const int icol = n - (n / 25) * 25;

    const u16* WH = (const u16*)(ws + (MODE ? WS_PSH : WS_PAH));
    const u16* WL = (const u16*)(ws + (MODE ? WS_PSL : WS_PAL));

    f32x4 acc[8];
    #pragma unroll
    for (int Mt = 0; Mt < 8; ++Mt) acc[Mt] = (f32x4){0.f, 0.f, 0.f, 0.f};

    const int ktEnd = (MODE == 0) ? 6 : 8;
    for (int kt = 0; kt < ktEnd; ++kt)
        frag_mma(kt, g, lane, mloc, icol, xt, pa_s, WH, WL, acc);

    if (MODE == 0) {
        const float* biasg = ws + WS_BIASY;
        // y stats
        #pragma unroll
        for (int Mt = 0; Mt < 8; ++Mt)
        #pragma unroll
        for (int r = 0; r < 4; ++r) {
            int o = Mt * 16 + g * 4 + r;
            float v = acc[Mt][r] + biasg[o * 25 + icol];
            float s = v, ss = v * v;
            #pragma unroll
            for (int mk = 1; mk < 16; mk <<= 1) {
                s += __shfl_xor(s, mk, 64); ss += __shfl_xor(ss, mk, 64);
            }
            if (l15 == 0) { atomicAdd(&stl[o], s); atomicAdd(&stl[128 + o], ss); }
        }
        // r pass
        #pragma unroll
        for (int Mt = 0; Mt < 8; ++Mt) acc[Mt] = (f32x4){0.f, 0.f, 0.f, 0.f};
        for (int kt = 6; kt < 8; ++kt)
            frag_mma(kt, g, lane, mloc, icol, xt, pa_s, WH, WL, acc);
        #pragma unroll
        for (int Mt = 0; Mt < 8; ++Mt)
        #pragma unroll
        for (int r = 0; r < 4; ++r) {
            int o = Mt * 16 + g * 4 + r;
            float v = acc[Mt][r] + br[o];
            float s = v, ss = v * v;
            #pragma unroll
            for (int mk = 1; mk < 16; mk <<= 1) {
                s += __shfl_xor(s, mk, 64); ss += __shfl_xor(ss, mk, 64);
            }
            if (l15 == 0) { atomicAdd(&stl[256 + o], s); atomicAdd(&stl[384 + o], ss); }
        }
        __syncthreads();
        if (tid < 512) atomicAdd(&ws[WS_STATS + tid], stl[tid]);
    } else {
        const float* C0g = ws + WS_C0;
        const int nbase = (n / 1600) * OB + (n - (n / 1600) * 1600);
        #pragma unroll
        for (int Mt = 0; Mt < 8; ++Mt)
        #pragma unroll
        for (int r = 0; r < 4; ++r) {
            int o = Mt * 16 + g * 4 + r;
            float v = acc[Mt][r] + C0g[o * 25 + icol];
            out[nbase + o * 1600] = fmaxf(v, 0.f);
        }
    }
}

__global__ void pass_b(const float* __restrict__ gamma, const float* __restrict__ beta,
                       const float* __restrict__ gamma_r, const float* __restrict__ beta_r,
                       const float* __restrict__ br, float* __restrict__ ws)
{
    int o = threadIdx.x;
    if (o >= 128) return;
    const float inv = 1.0f / 409600.0f;
    float* S = ws + WS_STATS;
    float my = S[o] * inv;
    float vy = S[128 + o] * inv - my * my;
    float ay = gamma[o] * rsqrtf(vy + 1e-5f);
    float by = beta[o] - ay * my;
    float mr = S[256 + o] * inv;
    float vr = S[384 + o] * inv - mr * mr;
    float ar = gamma_r[o] * rsqrtf(vr + 1e-5f);
    float brf = beta_r[o] - ar * mr;
    f32x4 a = {ay, by, ar, brf};
    *(f32x4*)(ws + WS_AFF + o * 4) = a;
    float cb = by + ar * br[o] + brf;
    for (int i = 0; i < 25; ++i)
        ws[WS_C0 + o * 25 + i] = fmaf(ay, ws[WS_BIASY + o * 25 + i], cb);
}

__global__ void pass_b2(const float* __restrict__ Wv, const float* __restrict__ Wr,
                        float* __restrict__ ws)
{
    int idx = blockIdx.x * blockDim.x + threadIdx.x;   // 32768 threads
    int k, o; decode_pack(idx, k, o);
    float w = (k < 192) ? Wv[(((k >> 6) * 128) + o) * 64 + (k & 63)]
                        : Wr[o * 64 + (k - 192)];
    float sc = (k < 192) ? ws[WS_AFF + o * 4 + 0] : ws[WS_AFF + o * 4 + 2];
    u16 hh, ll; split2(w * sc, hh, ll);
    ((u16*)(ws + WS_PSH))[idx] = hh;
    ((u16*)(ws + WS_PSL))[idx] = ll;
}

extern "C" void kernel_launch(void* const* d_in, const int* in_sizes, int n_in,
                              void* d_out, int out_size, void* d_ws, size_t ws_size,
                              hipStream_t stream) {
    const float* x       = (const float*)d_in[0];
    const float* PA      = (const float*)d_in[1];
    const float* Wv      = (const float*)d_in[2];
    const float* bv      = (const float*)d_in[3];
    const float* gamma   = (const float*)d_in[4];
    const float* beta    = (const float*)d_in[5];
    const float* Wr      = (const float*)d_in[6];
    const float* br      = (const float*)d_in[7];
    const float* gamma_r = (const float*)d_in[8];
    const float* beta_r  = (const float*)d_in[9];
    float* out = (float*)d_out;
    float* ws  = (float*)d_ws;

    prep<<<64, 256, 0, stream>>>(PA, Wv, bv, Wr, ws);
    gsa_main<0><<<NWG, 512, 0, stream>>>(x, PA, br, out, ws);
    pass_b<<<1, 128, 0, stream>>>(gamma, beta, gamma_r, beta_r, br, ws);
    pass_b2<<<64, 512, 0, stream>>>(Wv, Wr, ws);
    gsa_main<1><<<NWG, 512, 0, stream>>>(x, PA, br, out, ws);
}

// Round 3
// 759.895 us; speedup vs baseline: 2.1706x; 1.0943x over previous
//
#include <hip/hip_runtime.h>

typedef unsigned short u16;
typedef unsigned long long u64;
typedef float f32x4 __attribute__((ext_vector_type(4)));
typedef short bf16x8 __attribute__((ext_vector_type(8)));

// Shapes
#define XB 102400      // Cin*T*V per batch
#define TV 1600
#define OB 204800      // Cout*T*V per batch

// ws float offsets (all *4 bytes are 16B-multiples)
#define WS_PAPK_H 0        // PA packed B-frags hi: [3h][2ih][64l][8e] u16 = 3072 u16
#define WS_PAPK_L 1536
#define WS_WY_H   3072     // Wy packed A-frags hi: [6kt][8Mt][64l][8e] = 24576 u16
#define WS_WY_L   15360
#define WS_WR_H   27648    // Wr packed A-frags hi: [2kt][8Mt][64l][8e] = 8192 u16
#define WS_WR_L   31744
#define WS_BIASY  35840    // [128][25]
#define WS_C0     39040    // [128][25]
#define WS_AFF    42240    // [128][2] = (ay, ar)
#define WS_PART   42496    // [64 slots][512]
#define WS_RBUF   75264    // 52428800 floats (raw r)

// LDS strides (elements); all give 16B-aligned b128 frags + <=2-way bank conflicts
#define XS_S 136
#define XT_S 72
#define XA_S 200

__device__ __forceinline__ u16 f2bf(float x) {
    unsigned u = __float_as_uint(x);
    return (u16)((u + 0x7fffu + ((u >> 16) & 1u)) >> 16);
}
__device__ __forceinline__ void split2(float x, u16& h, u16& l) {
    h = f2bf(x);
    float hf = __uint_as_float(((unsigned)h) << 16);
    l = f2bf(x - hf);
}

__global__ void prep(const float* __restrict__ PA, const float* __restrict__ Wv,
                     const float* __restrict__ bv, const float* __restrict__ Wr,
                     float* __restrict__ ws)
{
    int tid = blockIdx.x * blockDim.x + threadIdx.x;
    int nthr = gridDim.x * blockDim.x;
    // PA B-frags: [h][ih][lane][e] = PA[h][i=ih*16+(l&15)][j=(l>>4)*8+e], zero-padded
    u16* PH = (u16*)(ws + WS_PAPK_H);
    u16* PL = (u16*)(ws + WS_PAPK_L);
    for (int idx = tid; idx < 3072; idx += nthr) {
        int e = idx & 7, l = (idx >> 3) & 63, ihw = (idx >> 9) & 1, h = idx >> 10;
        int i = ihw * 16 + (l & 15), j = ((l >> 4) << 3) + e;
        float v = (i < 25 && j < 25) ? PA[(h * 25 + i) * 25 + j] : 0.f;
        u16 hh, ll; split2(v, hh, ll);
        PH[idx] = hh; PL[idx] = ll;
    }
    // Wy A-frags: [kt][Mt][lane][e] = Wv[h][o][c], hc=kt*32+(l>>4)*8+e, o=Mt*16+(l&15)
    u16* YH = (u16*)(ws + WS_WY_H);
    u16* YL = (u16*)(ws + WS_WY_L);
    for (int idx = tid; idx < 24576; idx += nthr) {
        int e = idx & 7, l = (idx >> 3) & 63, Mt = (idx >> 9) & 7, kt = idx >> 12;
        int hc = kt * 32 + ((l >> 4) << 3) + e;
        int h = hc >> 6, c = hc & 63, o = Mt * 16 + (l & 15);
        float v = Wv[(h * 128 + o) * 64 + c];
        u16 hh, ll; split2(v, hh, ll);
        YH[idx] = hh; YL[idx] = ll;
    }
    // Wr A-frags: [kt][Mt][lane][e] = Wr[o][c], c=kt*32+(l>>4)*8+e
    u16* RH = (u16*)(ws + WS_WR_H);
    u16* RL = (u16*)(ws + WS_WR_L);
    for (int idx = tid; idx < 8192; idx += nthr) {
        int e = idx & 7, l = (idx >> 3) & 63, Mt = (idx >> 9) & 7, kt = idx >> 12;
        int c = kt * 32 + ((l >> 4) << 3) + e;
        int o = Mt * 16 + (l & 15);
        float v = Wr[o * 64 + c];
        u16 hh, ll; split2(v, hh, ll);
        RH[idx] = hh; RL[idx] = ll;
    }
    // biasY[o][i] = sum_h bv[h][o] * rowsum_j PA[h][i][j]
    for (int f = tid; f < 128 * 25; f += nthr) {
        int o = f / 25, i = f % 25;
        float s = 0.f;
        for (int h = 0; h < 3; ++h) {
            float rs = 0.f;
            for (int j = 0; j < 25; ++j) rs += PA[(h * 25 + i) * 25 + j];
            s = fmaf(bv[h * 128 + o], rs, s);
        }
        ws[WS_BIASY + f] = s;
    }
    for (int f = tid; f < 64 * 512; f += nthr) ws[WS_PART + f] = 0.f;
}

// One WG per 2 m-values (m = b*64+t). 512 threads = 8 waves.
// GEMM0: xa[h*64+c][i] = sum_j x[c][m,j]*PA[h][i][j]  (MFMA, hi/lo)
// GEMM1: y[o][m,i]     = sum_hc Wy[o][hc]*xa[hc][i]
// GEMM2: r[o][m,i]     = sum_c  Wr[o][c]*x[c][m,i]
__global__ __launch_bounds__(512, 4) void gsa_compute(
    const float* __restrict__ x, const float* __restrict__ br,
    float* __restrict__ out, float* __restrict__ ws)
{
    __shared__ u16 xs_h[64 * XS_S], xs_l[64 * XS_S];   // [c][mi*32+j]
    __shared__ u16 xt_h[64 * XT_S], xt_l[64 * XT_S];   // [mi*32+i][c]
    __shared__ u16 xa_h[32 * XA_S], xa_l[32 * XA_S];   // [i][hc]

    const int tid = threadIdx.x, wg = blockIdx.x;
    const int lane = tid & 63, w = tid >> 6;
    const int g = lane >> 4, l15 = lane & 15;
    const int m0 = wg * 2;

    // zero j-pads of xs (j=25..31) and i-pads of xt (i=25..31)
    for (int idx = tid; idx < 64 * 2 * 7; idx += 512) {
        int u = idx % 7, cm = idx / 7;
        int c = cm >> 1, mi = cm & 1;
        int off = c * XS_S + mi * 32 + 25 + u;
        xs_h[off] = 0; xs_l[off] = 0;
    }
    for (int idx = tid; idx < 2 * 7 * 72; idx += 512) {
        int mi = idx / 504, rr = idx % 504;
        int i = 25 + rr / 72, cc = rr % 72;
        int off = (mi * 32 + i) * XT_S + cc;
        xt_h[off] = 0; xt_l[off] = 0;
    }
    // stage x for 2 m's: bf16 hi/lo, both majors
    for (int idx = tid; idx < 896; idx += 512) {
        int mi = idx / 448, rem = idx - mi * 448;
        int c = rem / 7, q = rem - c * 7;
        int m = m0 + mi, b = m >> 6, t = m & 63;
        int g0 = (t * 25) >> 2;
        f32x4 v = *(const f32x4*)(x + b * XB + c * TV + (g0 + q) * 4);
        int jb = (g0 + q) * 4 - t * 25;
        #pragma unroll
        for (int u = 0; u < 4; ++u) {
            int j = jb + u;
            if (j >= 0 && j < 25) {
                u16 hh, ll; split2(v[u], hh, ll);
                xs_h[c * XS_S + mi * 32 + j] = hh;
                xs_l[c * XS_S + mi * 32 + j] = ll;
                xt_h[(mi * 32 + j) * XT_S + c] = hh;
                xt_l[(mi * 32 + j) * XT_S + c] = ll;
            }
        }
    }

    // persistent fragments
    const bf16x8* WYH = (const bf16x8*)(ws + WS_WY_H);
    const bf16x8* WYL = (const bf16x8*)(ws + WS_WY_L);
    const bf16x8* WRH = (const bf16x8*)(ws + WS_WR_H);
    const bf16x8* WRL = (const bf16x8*)(ws + WS_WR_L);
    const bf16x8* PAH = (const bf16x8*)(ws + WS_PAPK_H);
    const bf16x8* PAL = (const bf16x8*)(ws + WS_PAPK_L);

    bf16x8 wy_h[6];
    #pragma unroll
    for (int kt = 0; kt < 6; ++kt) wy_h[kt] = WYH[(kt * 8 + w) * 64 + lane];
    bf16x8 wr_h[2];
    #pragma unroll
    for (int kt = 0; kt < 2; ++kt) wr_h[kt] = WRH[(kt * 8 + w) * 64 + lane];
    const int ctw = w >> 1, ihw = w & 1;   // GEMM0 assignment
    bf16x8 pa_h[3], pa_l[3];
    #pragma unroll
    for (int h = 0; h < 3; ++h) {
        pa_h[h] = PAH[(h * 2 + ihw) * 64 + lane];
        pa_l[h] = PAL[(h * 2 + ihw) * 64 + lane];
    }
    // bias preloads (o = w*16 + g*4 + r_)
    float byv[2][4], brv[4];
    #pragma unroll
    for (int ih = 0; ih < 2; ++ih)
        #pragma unroll
        for (int r_ = 0; r_ < 4; ++r_) {
            int o = w * 16 + g * 4 + r_;
            int i = ih * 16 + l15; int ii = i < 25 ? i : 24;
            byv[ih][r_] = ws[WS_BIASY + o * 25 + ii];
        }
    #pragma unroll
    for (int r_ = 0; r_ < 4; ++r_) brv[r_] = br[w * 16 + g * 4 + r_];

    float psy[4] = {0,0,0,0}, pssy[4] = {0,0,0,0};
    float psr[4] = {0,0,0,0}, pssr[4] = {0,0,0,0};

    __syncthreads();

    for (int mi = 0; mi < 2; ++mi) {
        const int m = m0 + mi, b = m >> 6, t = m & 63;
        // ---- GEMM0 ----
        {
            bf16x8 a_h = *(const bf16x8*)(&xs_h[(ctw * 16 + l15) * XS_S + mi * 32 + g * 8]);
            bf16x8 a_l = *(const bf16x8*)(&xs_l[(ctw * 16 + l15) * XS_S + mi * 32 + g * 8]);
            int col = ihw * 16 + l15;
            #pragma unroll
            for (int h = 0; h < 3; ++h) {
                f32x4 a0 = {0.f, 0.f, 0.f, 0.f};
                a0 = __builtin_amdgcn_mfma_f32_16x16x32_bf16(a_h, pa_h[h], a0, 0, 0, 0);
                a0 = __builtin_amdgcn_mfma_f32_16x16x32_bf16(a_l, pa_h[h], a0, 0, 0, 0);
                a0 = __builtin_amdgcn_mfma_f32_16x16x32_bf16(a_h, pa_l[h], a0, 0, 0, 0);
                u64 hb = 0, lb = 0;
                #pragma unroll
                for (int r_ = 0; r_ < 4; ++r_) {
                    u16 hh, ll; split2(a0[r_], hh, ll);
                    hb |= ((u64)hh) << (16 * r_);
                    lb |= ((u64)ll) << (16 * r_);
                }
                int hc0 = h * 64 + ctw * 16 + g * 4;
                *(u64*)(&xa_h[col * XA_S + hc0]) = hb;
                *(u64*)(&xa_l[col * XA_S + hc0]) = lb;
            }
        }
        __syncthreads();
        // ---- GEMM1 (y) + GEMM2 (r), wave w owns Mt=w ----
        #pragma unroll
        for (int ih = 0; ih < 2; ++ih) {
            const int i = ih * 16 + l15;
            f32x4 accy = {0.f, 0.f, 0.f, 0.f};
            #pragma unroll
            for (int kt = 0; kt < 6; ++kt) {
                bf16x8 b_h = *(const bf16x8*)(&xa_h[i * XA_S + kt * 32 + g * 8]);
                bf16x8 b_l = *(const bf16x8*)(&xa_l[i * XA_S + kt * 32 + g * 8]);
                bf16x8 wl = WYL[(kt * 8 + w) * 64 + lane];
                accy = __builtin_amdgcn_mfma_f32_16x16x32_bf16(wy_h[kt], b_h, accy, 0, 0, 0);
                accy = __builtin_amdgcn_mfma_f32_16x16x32_bf16(wy_h[kt], b_l, accy, 0, 0, 0);
                accy = __builtin_amdgcn_mfma_f32_16x16x32_bf16(wl, b_h, accy, 0, 0, 0);
            }
            f32x4 accr = {0.f, 0.f, 0.f, 0.f};
            #pragma unroll
            for (int kt = 0; kt < 2; ++kt) {
                bf16x8 b_h = *(const bf16x8*)(&xt_h[(mi * 32 + i) * XT_S + kt * 32 + g * 8]);
                bf16x8 b_l = *(const bf16x8*)(&xt_l[(mi * 32 + i) * XT_S + kt * 32 + g * 8]);
                bf16x8 wl = WRL[(kt * 8 + w) * 64 + lane];
                accr = __builtin_amdgcn_mfma_f32_16x16x32_bf16(wr_h[kt], b_h, accr, 0, 0, 0);
                accr = __builtin_amdgcn_mfma_f32_16x16x32_bf16(wr_h[kt], b_l, accr, 0, 0, 0);
                accr = __builtin_amdgcn_mfma_f32_16x16x32_bf16(wl, b_h, accr, 0, 0, 0);
            }
            const bool valid = (i < 25);
            const int obase = b * OB + t * 25 + i;
            #pragma unroll
            for (int r_ = 0; r_ < 4; ++r_) {
                int o = w * 16 + g * 4 + r_;
                float vy = accy[r_], vr = accr[r_];
                if (valid) {
                    float vys = vy + byv[ih][r_];
                    float vrs = vr + brv[r_];
                    psy[r_] += vys;  pssy[r_] = fmaf(vys, vys, pssy[r_]);
                    psr[r_] += vrs;  pssr[r_] = fmaf(vrs, vrs, pssr[r_]);
                    out[obase + o * 1600] = vy;                 // raw y
                    ws[WS_RBUF + obase + o * 1600] = vr;        // raw r
                }
            }
        }
        __syncthreads();
    }

    // stats flush: reduce over the 16 i-lanes, then slot-spread atomics
    #pragma unroll
    for (int r_ = 0; r_ < 4; ++r_) {
        float a = psy[r_], bq = pssy[r_], cq = psr[r_], dq = pssr[r_];
        #pragma unroll
        for (int mk = 1; mk < 16; mk <<= 1) {
            a += __shfl_xor(a, mk, 64);  bq += __shfl_xor(bq, mk, 64);
            cq += __shfl_xor(cq, mk, 64); dq += __shfl_xor(dq, mk, 64);
        }
        if (l15 == 0) {
            int o = w * 16 + g * 4 + r_;
            float* P = ws + WS_PART + (size_t)(wg & 63) * 512;
            atomicAdd(&P[o], a);        atomicAdd(&P[128 + o], bq);
            atomicAdd(&P[256 + o], cq); atomicAdd(&P[384 + o], dq);
        }
    }
}

__global__ void pass_b(const float* __restrict__ gamma, const float* __restrict__ beta,
                       const float* __restrict__ gamma_r, const float* __restrict__ beta_r,
                       const float* __restrict__ br, float* __restrict__ ws)
{
    __shared__ float sums[512];
    int tid = threadIdx.x;
    float s = 0.f;
    for (int k = 0; k < 64; ++k) s += ws[WS_PART + k * 512 + tid];
    sums[tid] = s;
    __syncthreads();
    if (tid < 128) {
        int o = tid;
        const float inv = 1.0f / 409600.0f;
        float my = sums[o] * inv;
        float vy = sums[128 + o] * inv - my * my;
        float ay = gamma[o] * rsqrtf(vy + 1e-5f);
        float by = beta[o] - ay * my;
        float mr = sums[256 + o] * inv;
        float vr = sums[384 + o] * inv - mr * mr;
        float ar = gamma_r[o] * rsqrtf(vr + 1e-5f);
        float brf = beta_r[o] - ar * mr;
        ws[WS_AFF + o * 2] = ay;
        ws[WS_AFF + o * 2 + 1] = ar;
        float cb = by + ar * br[o] + brf;
        for (int i = 0; i < 25; ++i)
            ws[WS_C0 + o * 25 + i] = fmaf(ay, ws[WS_BIASY + o * 25 + i], cb);
    }
}

__global__ __launch_bounds__(256) void finish(float* __restrict__ out, const float* __restrict__ ws)
{
    const f32x4* __restrict__ rb = (const f32x4*)(ws + WS_RBUF);
    f32x4* __restrict__ o4 = (f32x4*)out;
    const float* __restrict__ C0 = ws + WS_C0;
    const float* __restrict__ AF = ws + WS_AFF;
    for (int i4 = blockIdx.x * 256 + threadIdx.x; i4 < 13107200; i4 += gridDim.x * 256) {
        f32x4 y = o4[i4];
        f32x4 r = rb[i4];
        int row = i4 / 400;               // b*128 + o
        int o = row & 127;
        int ti = (i4 - row * 400) * 4;    // t*25 + i, 0..1596
        int iq = (ti * 5243) >> 17;       // exact ti/25 for ti<1600
        int i = ti - iq * 25;
        float ay = AF[o * 2], ar = AF[o * 2 + 1];
        f32x4 res;
        #pragma unroll
        for (int u = 0; u < 4; ++u) {
            int ii = i + u; ii -= (ii >= 25) ? 25 : 0;
            res[u] = fmaxf(0.f, fmaf(ay, y[u], fmaf(ar, r[u], C0[o * 25 + ii])));
        }
        o4[i4] = res;
    }
}

extern "C" void kernel_launch(void* const* d_in, const int* in_sizes, int n_in,
                              void* d_out, int out_size, void* d_ws, size_t ws_size,
                              hipStream_t stream) {
    const float* x       = (const float*)d_in[0];
    const float* PA      = (const float*)d_in[1];
    const float* Wv      = (const float*)d_in[2];
    const float* bv      = (const float*)d_in[3];
    const float* gamma   = (const float*)d_in[4];
    const float* beta    = (const float*)d_in[5];
    const float* Wr      = (const float*)d_in[6];
    const float* br      = (const float*)d_in[7];
    const float* gamma_r = (const float*)d_in[8];
    const float* beta_r  = (const float*)d_in[9];
    float* out = (float*)d_out;
    float* ws  = (float*)d_ws;

    prep<<<64, 256, 0, stream>>>(PA, Wv, bv, Wr, ws);
    gsa_compute<<<8192, 512, 0, stream>>>(x, br, out, ws);
    pass_b<<<1, 512, 0, stream>>>(gamma, beta, gamma_r, beta_r, br, ws);
    finish<<<2048, 256, 0, stream>>>(out, ws);
}